// Round 5
// baseline (131.313 us; speedup 1.0000x reference)
//
#include <hip/hip_runtime.h>
#include <hip/hip_bf16.h>

#define BATCH     16384
#define INFEAT    4096
#define NCHUNK    8
#define CIN       512
#define COUT      512
#define ACT_GRID  2048
#define ROWS_PER_BLOCK (BATCH / ACT_GRID)   // 8
#define OUT_MAIN  (BATCH * 1024)            // 16777216 f32 elements

typedef short bf16x8 __attribute__((ext_vector_type(8)));
typedef float f32x4  __attribute__((ext_vector_type(4)));

static __device__ inline unsigned short f2bf_rne(float f) {
    unsigned int u = __builtin_bit_cast(unsigned int, f);
    unsigned int r = (u + 0x7fffu + ((u >> 16) & 1u)) >> 16;
    return (unsigned short)r;
}

// ---------------- Stage 1: per-block partial abs-sums (no atomics) ----------------
__global__ __launch_bounds__(256, 4)
void act_partial_kernel(const float* __restrict__ x, float* __restrict__ part) {
    int t = threadIdx.x;
    float acc[4] = {0.f, 0.f, 0.f, 0.f};
    int r0 = blockIdx.x * ROWS_PER_BLOCK;
    for (int r = 0; r < ROWS_PER_BLOCK; ++r) {
        const float4* p = reinterpret_cast<const float4*>(x + (size_t)(r0 + r) * INFEAT);
#pragma unroll
        for (int c = 0; c < 4; ++c) {
            float4 v = p[c * 256 + t];
            acc[c] += fabsf(v.x) + fabsf(v.y) + fabsf(v.z) + fabsf(v.w);
        }
    }
#pragma unroll
    for (int c = 0; c < 4; ++c) {
        float v = acc[c];
        v += __shfl_xor(v, 32);
        v += __shfl_xor(v, 16);
        v += __shfl_xor(v, 8);
        v += __shfl_xor(v, 4);
        v += __shfl_xor(v, 2);
        v += __shfl_xor(v, 1);
        acc[c] = v;
    }
    __shared__ float sred[16];
    int wave = t >> 6, lane = t & 63;
    if (lane == 0) {
#pragma unroll
        for (int c = 0; c < 4; ++c) sred[wave * 4 + c] = acc[c];
    }
    __syncthreads();
    if (t < 8) {
        int c = t >> 1, hi = t & 1;
        float s = sred[(2 * hi) * 4 + c] + sred[(2 * hi + 1) * 4 + c];
        part[blockIdx.x * 8 + t] = s;
    }
}

// ---------------- Stage 2: final reduce (f64), top-2, write outputs (f32) ----------------
__global__ void finalize_topk_kernel(const float* __restrict__ part,
                                     float* __restrict__ out_act,   // 8 f32
                                     float* __restrict__ out_idx,   // 2 f32
                                     int* __restrict__ ws_idx) {
    int t = threadIdx.x;
    __shared__ double sd[256];
    __shared__ double act[8];
    int k = t & 7, s = t >> 3;
    double a = 0.0;
    for (int i = s; i < ACT_GRID; i += 32) a += (double)part[i * 8 + k];
    sd[t] = a;
    __syncthreads();
    if (t < 8) {
        double tot = 0.0;
        for (int j = 0; j < 32; ++j) tot += sd[t + 8 * j];
        double m = tot / ((double)BATCH * (double)CIN);
        act[t] = m;
        out_act[t] = (float)m;
    }
    __syncthreads();
    if (t == 0) {
        int i0 = 0;
        for (int i = 1; i < 8; ++i) if (act[i] > act[i0]) i0 = i;
        int i1 = -1;
        for (int i = 0; i < 8; ++i) {
            if (i == i0) continue;
            if (i1 < 0 || act[i] > act[i1]) i1 = i;
        }
        out_idx[0] = (float)i0;
        out_idx[1] = (float)i1;
        ws_idx[0] = i0;
        ws_idx[1] = i1;
    }
}

// ---------------- Stage 3a: transpose+convert selected W chunks to bf16 (n-major) ----------------
__global__ void wtrans_kernel(const float* __restrict__ W, const int* __restrict__ idx,
                              unsigned short* __restrict__ WT) {
    int c = blockIdx.z;
    int id = idx[c];
    __shared__ float tile[32][33];
    int tx = threadIdx.x, ty = threadIdx.y;
    const float* Wp = W + (size_t)id * (CIN * COUT);
    int i0 = blockIdx.x * 32, o0 = blockIdx.y * 32;
#pragma unroll
    for (int r = 0; r < 4; ++r)
        tile[ty + r * 8][tx] = Wp[(size_t)(i0 + ty + r * 8) * COUT + o0 + tx];
    __syncthreads();
    unsigned short* WTp = WT + (size_t)c * (CIN * COUT);
#pragma unroll
    for (int r = 0; r < 4; ++r)
        WTp[(size_t)(o0 + ty + r * 8) * CIN + i0 + tx] = f2bf_rne(tile[tx][ty + r * 8]);
}

// ---------------- Stage 3b: GEMM 256x128, BK=32, dbuf LDS, 1 barrier/kt, reg prefetch ----------------
#define BM 256
#define BN 128
#define LDA 40   // padded row stride in shorts (80 B): 2-way (free) frag reads, uniform stage writes
__global__ __launch_bounds__(256, 2)
void gemm_topk_kernel(const float* __restrict__ x, const unsigned short* __restrict__ WT,
                      const float* __restrict__ bvec, const int* __restrict__ idxp,
                      float* __restrict__ out) {
    __shared__ __align__(16) unsigned short As[2][BM * LDA];   // 2 x 20 KB
    __shared__ __align__(16) unsigned short Bs[2][BN * LDA];   // 2 x 10 KB

    int c = blockIdx.z;
    int idx = idxp[c];
    int brow = blockIdx.x * BM;
    int bn   = blockIdx.y * BN;
    int t = threadIdx.x;
    int lane = t & 63, wid = t >> 6;
    int wm = wid >> 1, wn = wid & 1;          // wave tile 128x64
    int lrow = lane & 15, lgrp = lane >> 4;

    f32x4 acc[8][4] = {};

    const float* xbase = x + (size_t)brow * INFEAT + idx * CIN;
    const unsigned short* wtbase = WT + (size_t)c * (CIN * COUT);

    // A staging: thread t -> rows p*64 + (t>>2), k-slot (t&3)*8 (8 floats = 32 B)
    int sa_r = t >> 2, sa_k = (t & 3) * 8;
    // B staging: thread t -> row t>>1, half (t&1)*16 shorts (32 B)
    int sb_n = t >> 1, sb_h = (t & 1) * 16;

    float4 pa[4][2];   // prefetch regs: 4 passes x 2 float4
    uint4  pb[2];

#define LOAD_TILE(kt)                                                                  \
    {                                                                                  \
        int k0 = (kt) * 32;                                                            \
        _Pragma("unroll")                                                              \
        for (int p = 0; p < 4; ++p) {                                                  \
            const float* src = xbase + (size_t)(p * 64 + sa_r) * INFEAT + k0 + sa_k;   \
            pa[p][0] = *reinterpret_cast<const float4*>(src);                          \
            pa[p][1] = *reinterpret_cast<const float4*>(src + 4);                      \
        }                                                                              \
        const unsigned short* bsrc = wtbase + (size_t)(bn + sb_n) * CIN + k0 + sb_h;   \
        pb[0] = *reinterpret_cast<const uint4*>(bsrc);                                 \
        pb[1] = *reinterpret_cast<const uint4*>(bsrc + 8);                             \
    }

#define CVT_WRITE(buf)                                                                 \
    {                                                                                  \
        _Pragma("unroll")                                                              \
        for (int p = 0; p < 4; ++p) {                                                  \
            ushort4 s0, s1;                                                            \
            s0.x = f2bf_rne(pa[p][0].x); s0.y = f2bf_rne(pa[p][0].y);                  \
            s0.z = f2bf_rne(pa[p][0].z); s0.w = f2bf_rne(pa[p][0].w);                  \
            s1.x = f2bf_rne(pa[p][1].x); s1.y = f2bf_rne(pa[p][1].y);                  \
            s1.z = f2bf_rne(pa[p][1].z); s1.w = f2bf_rne(pa[p][1].w);                  \
            unsigned short* dst = &As[buf][(p * 64 + sa_r) * LDA + sa_k];              \
            *reinterpret_cast<ushort4*>(dst)     = s0;                                 \
            *reinterpret_cast<ushort4*>(dst + 4) = s1;                                 \
        }                                                                              \
        unsigned short* bdst = &Bs[buf][sb_n * LDA + sb_h];                            \
        *reinterpret_cast<uint4*>(bdst)     = pb[0];                                   \
        *reinterpret_cast<uint4*>(bdst + 8) = pb[1];                                   \
    }

    // prologue: stage kt=0 into buf 0
    LOAD_TILE(0);
    CVT_WRITE(0);
    int cur = 0;

    for (int kt = 0; kt < 16; ++kt) {
        if (kt < 15) LOAD_TILE(kt + 1);          // in flight across the barrier
        __syncthreads();                          // buf[cur] ready, buf[cur^1] free
        bf16x8 af[8], bfr[4];
#pragma unroll
        for (int mi = 0; mi < 8; ++mi)
            af[mi] = *reinterpret_cast<const bf16x8*>(&As[cur][(wm * 128 + mi * 16 + lrow) * LDA + lgrp * 8]);
#pragma unroll
        for (int ni = 0; ni < 4; ++ni)
            bfr[ni] = *reinterpret_cast<const bf16x8*>(&Bs[cur][(wn * 64 + ni * 16 + lrow) * LDA + lgrp * 8]);
        if (kt < 15) CVT_WRITE(cur ^ 1);          // waits vmcnt for prefetched regs
#pragma unroll
        for (int mi = 0; mi < 8; ++mi)
#pragma unroll
            for (int ni = 0; ni < 4; ++ni)
                acc[mi][ni] = __builtin_amdgcn_mfma_f32_16x16x32_bf16(af[mi], bfr[ni], acc[mi][ni], 0, 0, 0);
        cur ^= 1;
    }

    // epilogue: add bias, write f32 C. D layout: row=(lane>>4)*4+reg, col=lane&15
    float bias[4];
#pragma unroll
    for (int ni = 0; ni < 4; ++ni)
        bias[ni] = bvec[idx * COUT + bn + wn * 64 + ni * 16 + lrow];
#pragma unroll
    for (int mi = 0; mi < 8; ++mi) {
#pragma unroll
        for (int r = 0; r < 4; ++r) {
            int row = brow + wm * 128 + mi * 16 + lgrp * 4 + r;
            float* orow = out + (size_t)row * 1024 + c * 512 + bn + wn * 64;
#pragma unroll
            for (int ni = 0; ni < 4; ++ni)
                orow[ni * 16 + lrow] = acc[mi][ni][r] + bias[ni];
        }
    }
#undef LOAD_TILE
#undef CVT_WRITE
}

extern "C" void kernel_launch(void* const* d_in, const int* in_sizes, int n_in,
                              void* d_out, int out_size, void* d_ws, size_t ws_size,
                              hipStream_t stream) {
    const float* x = (const float*)d_in[0];
    const float* W = (const float*)d_in[1];
    const float* b = (const float*)d_in[2];
    float* out = (float*)d_out;

    float* part = (float*)d_ws;
    int* ws_idx = (int*)((char*)d_ws + 65536);
    unsigned short* WT = (unsigned short*)((char*)d_ws + 65536 + 256);

    act_partial_kernel<<<ACT_GRID, 256, 0, stream>>>(x, part);
    finalize_topk_kernel<<<1, 256, 0, stream>>>(part, out + OUT_MAIN, out + OUT_MAIN + 8, ws_idx);
    wtrans_kernel<<<dim3(16, 16, 2), dim3(32, 8), 0, stream>>>(W, ws_idx, WT);
    gemm_topk_kernel<<<dim3(BATCH / BM, COUT / BN, 2), 256, 0, stream>>>(x, WT, b, ws_idx, out);
}

// Round 6
// 127.789 us; speedup vs baseline: 1.0276x; 1.0276x over previous
//
#include <hip/hip_runtime.h>
#include <hip/hip_bf16.h>

#define BATCH     16384
#define INFEAT    4096
#define NCHUNK    8
#define CIN       512
#define COUT      512
#define ACT_GRID  2048
#define ROWS_PER_BLOCK (BATCH / ACT_GRID)   // 8
#define OUT_MAIN  (BATCH * 1024)            // 16777216 f32 elements

typedef short bf16x8 __attribute__((ext_vector_type(8)));
typedef float f32x4  __attribute__((ext_vector_type(4)));

static __device__ inline unsigned short f2bf_rne(float f) {
    unsigned int u = __builtin_bit_cast(unsigned int, f);
    unsigned int r = (u + 0x7fffu + ((u >> 16) & 1u)) >> 16;
    return (unsigned short)r;
}

// ---------------- Stage 1: per-block partial abs-sums (no atomics) ----------------
__global__ __launch_bounds__(256, 4)
void act_partial_kernel(const float* __restrict__ x, float* __restrict__ part) {
    int t = threadIdx.x;
    float acc[4] = {0.f, 0.f, 0.f, 0.f};
    int r0 = blockIdx.x * ROWS_PER_BLOCK;
    for (int r = 0; r < ROWS_PER_BLOCK; ++r) {
        const float4* p = reinterpret_cast<const float4*>(x + (size_t)(r0 + r) * INFEAT);
#pragma unroll
        for (int c = 0; c < 4; ++c) {
            float4 v = p[c * 256 + t];
            acc[c] += fabsf(v.x) + fabsf(v.y) + fabsf(v.z) + fabsf(v.w);
        }
    }
#pragma unroll
    for (int c = 0; c < 4; ++c) {
        float v = acc[c];
        v += __shfl_xor(v, 32);
        v += __shfl_xor(v, 16);
        v += __shfl_xor(v, 8);
        v += __shfl_xor(v, 4);
        v += __shfl_xor(v, 2);
        v += __shfl_xor(v, 1);
        acc[c] = v;
    }
    __shared__ float sred[16];
    int wave = t >> 6, lane = t & 63;
    if (lane == 0) {
#pragma unroll
        for (int c = 0; c < 4; ++c) sred[wave * 4 + c] = acc[c];
    }
    __syncthreads();
    if (t < 8) {
        int c = t >> 1, hi = t & 1;
        float s = sred[(2 * hi) * 4 + c] + sred[(2 * hi + 1) * 4 + c];
        part[blockIdx.x * 8 + t] = s;
    }
}

// ---------------- Stage 2: final reduce (f64), top-2, write outputs (f32) ----------------
__global__ void finalize_topk_kernel(const float* __restrict__ part,
                                     float* __restrict__ out_act,   // 8 f32
                                     float* __restrict__ out_idx,   // 2 f32
                                     int* __restrict__ ws_idx) {
    int t = threadIdx.x;
    __shared__ double sd[256];
    __shared__ double act[8];
    int k = t & 7, s = t >> 3;
    double a = 0.0;
    for (int i = s; i < ACT_GRID; i += 32) a += (double)part[i * 8 + k];
    sd[t] = a;
    __syncthreads();
    if (t < 8) {
        double tot = 0.0;
        for (int j = 0; j < 32; ++j) tot += sd[t + 8 * j];
        double m = tot / ((double)BATCH * (double)CIN);
        act[t] = m;
        out_act[t] = (float)m;
    }
    __syncthreads();
    if (t == 0) {
        int i0 = 0;
        for (int i = 1; i < 8; ++i) if (act[i] > act[i0]) i0 = i;
        int i1 = -1;
        for (int i = 0; i < 8; ++i) {
            if (i == i0) continue;
            if (i1 < 0 || act[i] > act[i1]) i1 = i;
        }
        out_idx[0] = (float)i0;
        out_idx[1] = (float)i1;
        ws_idx[0] = i0;
        ws_idx[1] = i1;
    }
}

// ---------------- Stage 3a: transpose+convert selected W chunks to bf16 (n-major) ----------------
__global__ void wtrans_kernel(const float* __restrict__ W, const int* __restrict__ idx,
                              unsigned short* __restrict__ WT) {
    int c = blockIdx.z;
    int id = idx[c];
    __shared__ float tile[32][33];
    int tx = threadIdx.x, ty = threadIdx.y;
    const float* Wp = W + (size_t)id * (CIN * COUT);
    int i0 = blockIdx.x * 32, o0 = blockIdx.y * 32;
#pragma unroll
    for (int r = 0; r < 4; ++r)
        tile[ty + r * 8][tx] = Wp[(size_t)(i0 + ty + r * 8) * COUT + o0 + tx];
    __syncthreads();
    unsigned short* WTp = WT + (size_t)c * (CIN * COUT);
#pragma unroll
    for (int r = 0; r < 4; ++r)
        WTp[(size_t)(o0 + ty + r * 8) * CIN + i0 + tx] = f2bf_rne(tile[tx][ty + r * 8]);
}

// ---------------- Stage 3b: gather selected x chunks -> bf16 (k-major) ----------------
// XB[c][r][k] = bf16(x[r][idx[c]*512 + k]); 8 elems/thread
__global__ __launch_bounds__(256, 4)
void xsel_kernel(const float* __restrict__ x, const int* __restrict__ idxp,
                 unsigned short* __restrict__ XB) {
    int c = blockIdx.y;
    int idx = idxp[c];
    size_t e0 = ((size_t)blockIdx.x * 256 + threadIdx.x) * 8;   // within 16384*512
    int r = (int)(e0 >> 9);
    int k = (int)(e0 & 511);
    const float* src = x + (size_t)r * INFEAT + idx * CIN + k;
    float4 v0 = *reinterpret_cast<const float4*>(src);
    float4 v1 = *reinterpret_cast<const float4*>(src + 4);
    ushort4 s0, s1;
    s0.x = f2bf_rne(v0.x); s0.y = f2bf_rne(v0.y); s0.z = f2bf_rne(v0.z); s0.w = f2bf_rne(v0.w);
    s1.x = f2bf_rne(v1.x); s1.y = f2bf_rne(v1.y); s1.z = f2bf_rne(v1.z); s1.w = f2bf_rne(v1.w);
    unsigned short* dst = XB + (size_t)c * (BATCH * CIN) + e0;
    *reinterpret_cast<ushort4*>(dst)     = s0;
    *reinterpret_cast<ushort4*>(dst + 4) = s1;
}

// ---------------- Stage 3c: GEMM (bf16 MFMA), 128x128 tile, BK=32, bf16 A+B, f32 out ----------------
#define LDA 40   // padded row stride in shorts (80 B): conflict-free-ish frag reads
__global__ __launch_bounds__(256, 2)
void gemm_topk_kernel(const unsigned short* __restrict__ XB, const unsigned short* __restrict__ WT,
                      const float* __restrict__ bvec, const int* __restrict__ idxp,
                      float* __restrict__ out) {
    __shared__ __align__(16) unsigned short As[128 * LDA];
    __shared__ __align__(16) unsigned short Bs[128 * LDA];

    int c = blockIdx.z;
    int idx = idxp[c];
    int brow = blockIdx.x * 128;
    int bn   = blockIdx.y * 128;
    int t = threadIdx.x;
    int lane = t & 63, wid = t >> 6;
    int wm = wid >> 1, wn = wid & 1;
    int lrow = lane & 15, lgrp = lane >> 4;

    f32x4 acc[4][4] = {};

    const unsigned short* xbase = XB + (size_t)c * (BATCH * CIN) + (size_t)brow * CIN;
    const unsigned short* wtbase = WT + (size_t)c * (CIN * COUT);

    // staging: thread t -> row t>>1 (0..127), 16-short half (t&1)
    int sr = t >> 1, sh = (t & 1) * 16;

    for (int kt = 0; kt < 16; ++kt) {
        int k0 = kt * 32;
        __syncthreads();
        {
            const unsigned short* asrc = xbase + (size_t)sr * CIN + k0 + sh;
            uint4 a0 = *reinterpret_cast<const uint4*>(asrc);
            uint4 a1 = *reinterpret_cast<const uint4*>(asrc + 8);
            const unsigned short* bsrc = wtbase + (size_t)(bn + sr) * CIN + k0 + sh;
            uint4 b0 = *reinterpret_cast<const uint4*>(bsrc);
            uint4 b1 = *reinterpret_cast<const uint4*>(bsrc + 8);
            unsigned short* adst = &As[sr * LDA + sh];
            *reinterpret_cast<uint4*>(adst)     = a0;
            *reinterpret_cast<uint4*>(adst + 8) = a1;
            unsigned short* bdst = &Bs[sr * LDA + sh];
            *reinterpret_cast<uint4*>(bdst)     = b0;
            *reinterpret_cast<uint4*>(bdst + 8) = b1;
        }
        __syncthreads();
        bf16x8 af[4], bfr[4];
#pragma unroll
        for (int mi = 0; mi < 4; ++mi)
            af[mi] = *reinterpret_cast<const bf16x8*>(&As[(wm * 64 + mi * 16 + lrow) * LDA + lgrp * 8]);
#pragma unroll
        for (int ni = 0; ni < 4; ++ni)
            bfr[ni] = *reinterpret_cast<const bf16x8*>(&Bs[(wn * 64 + ni * 16 + lrow) * LDA + lgrp * 8]);
#pragma unroll
        for (int mi = 0; mi < 4; ++mi)
#pragma unroll
            for (int ni = 0; ni < 4; ++ni)
                acc[mi][ni] = __builtin_amdgcn_mfma_f32_16x16x32_bf16(af[mi], bfr[ni], acc[mi][ni], 0, 0, 0);
    }

    // epilogue: add bias, write f32 C. D layout: row=(lane>>4)*4+reg, col=lane&15
    float bias[4];
#pragma unroll
    for (int ni = 0; ni < 4; ++ni)
        bias[ni] = bvec[idx * COUT + bn + wn * 64 + ni * 16 + lrow];
#pragma unroll
    for (int mi = 0; mi < 4; ++mi) {
#pragma unroll
        for (int r = 0; r < 4; ++r) {
            int row = brow + wm * 64 + mi * 16 + lgrp * 4 + r;
            float* orow = out + (size_t)row * 1024 + c * 512 + bn + wn * 64;
#pragma unroll
            for (int ni = 0; ni < 4; ++ni)
                orow[ni * 16 + lrow] = acc[mi][ni][r] + bias[ni];
        }
    }
}

extern "C" void kernel_launch(void* const* d_in, const int* in_sizes, int n_in,
                              void* d_out, int out_size, void* d_ws, size_t ws_size,
                              hipStream_t stream) {
    const float* x = (const float*)d_in[0];
    const float* W = (const float*)d_in[1];
    const float* b = (const float*)d_in[2];
    float* out = (float*)d_out;

    // ws layout: [0,64K) partials; [64K,+256) topk ints; [65792,+1M) WT; then XB (32 MB)
    float* part = (float*)d_ws;
    int* ws_idx = (int*)((char*)d_ws + 65536);
    unsigned short* WT = (unsigned short*)((char*)d_ws + 65792);
    unsigned short* XB = (unsigned short*)((char*)d_ws + 65792 + 2 * CIN * COUT * 2);

    act_partial_kernel<<<ACT_GRID, 256, 0, stream>>>(x, part);
    finalize_topk_kernel<<<1, 256, 0, stream>>>(part, out + OUT_MAIN, out + OUT_MAIN + 8, ws_idx);
    wtrans_kernel<<<dim3(16, 16, 2), dim3(32, 8), 0, stream>>>(W, ws_idx, WT);
    xsel_kernel<<<dim3(BATCH * CIN / (256 * 8), 2), 256, 0, stream>>>(x, ws_idx, XB);
    gemm_topk_kernel<<<dim3(BATCH / 128, COUT / 128, 2), 256, 0, stream>>>(XB, WT, b, ws_idx, out);
}